// Round 1
// baseline (611.517 us; speedup 1.0000x reference)
//
#include <hip/hip_runtime.h>
#include <hip/hip_bf16.h>
#include <stdint.h>

#define M_DIM 8192
#define K_DIM 4096
#define N_DIM 4096

typedef __attribute__((ext_vector_type(8))) short short8;
typedef __attribute__((ext_vector_type(4))) float floatx4;

// ---------------- per-row abs-mean scale ----------------
__global__ void row_scale_kernel(const float* __restrict__ w, float* __restrict__ scales) {
    int row = blockIdx.x;
    const float4* wr = (const float4*)(w + (size_t)row * K_DIM);
    double s = 0.0;
    for (int i = threadIdx.x; i < K_DIM / 4; i += 256) {
        float4 v = wr[i];
        s += (double)fabsf(v.x) + (double)fabsf(v.y) + (double)fabsf(v.z) + (double)fabsf(v.w);
    }
    #pragma unroll
    for (int off = 32; off > 0; off >>= 1) s += __shfl_down(s, off);
    __shared__ double partial[4];
    int wave = threadIdx.x >> 6;
    if ((threadIdx.x & 63) == 0) partial[wave] = s;
    __syncthreads();
    if (threadIdx.x == 0) {
        double t = partial[0] + partial[1] + partial[2] + partial[3];
        float m = (float)(t / (double)K_DIM);
        scales[row] = fmaxf(m, 1e-5f);
    }
}

// ---------------- quantize weight to ternary bf16 ----------------
__global__ void quant_kernel(const float* __restrict__ w, const float* __restrict__ scales,
                             __hip_bfloat16* __restrict__ qb) {
    int v = blockIdx.x * blockDim.x + threadIdx.x;  // over K_DIM*N_DIM/4 float4s
    float4 wv = ((const float4*)w)[v];
    float s = scales[v >> 10];  // 1024 float4s per row of 4096
    float q0 = fminf(fmaxf(rintf(wv.x / s), -1.f), 1.f);
    float q1 = fminf(fmaxf(rintf(wv.y / s), -1.f), 1.f);
    float q2 = fminf(fmaxf(rintf(wv.z / s), -1.f), 1.f);
    float q3 = fminf(fmaxf(rintf(wv.w / s), -1.f), 1.f);
    __hip_bfloat16 o[4] = {__float2bfloat16(q0), __float2bfloat16(q1),
                           __float2bfloat16(q2), __float2bfloat16(q3)};
    *(uint2*)(qb + 4 * (size_t)v) = *(uint2*)o;
}

// ---------------- x fp32 -> bf16 ----------------
__global__ void xconv_kernel(const float* __restrict__ x, __hip_bfloat16* __restrict__ xb) {
    int v = blockIdx.x * blockDim.x + threadIdx.x;  // over M_DIM*K_DIM/4 float4s
    float4 xv = ((const float4*)x)[v];
    __hip_bfloat16 o[4] = {__float2bfloat16(xv.x), __float2bfloat16(xv.y),
                           __float2bfloat16(xv.z), __float2bfloat16(xv.w)};
    *(uint2*)(xb + 4 * (size_t)v) = *(uint2*)o;
}

// ---------------- bf16 MFMA GEMM: out = xb @ qb^T * scale[col] ----------------
__device__ __forceinline__ void load16(const void* g, void* l) {
    __builtin_amdgcn_global_load_lds((const __attribute__((address_space(1))) uint32_t*)g,
                                     (__attribute__((address_space(3))) uint32_t*)l, 16, 0, 0);
}

__global__ __launch_bounds__(256) void gemm_kernel(const __hip_bfloat16* __restrict__ xb,
                                                   const __hip_bfloat16* __restrict__ qb,
                                                   const float* __restrict__ scales,
                                                   float* __restrict__ out) {
    __shared__ __align__(16) __hip_bfloat16 lsA[128 * 32];
    __shared__ __align__(16) __hip_bfloat16 lsB[128 * 32];
    int tid = threadIdx.x;
    int lane = tid & 63;
    int wave = tid >> 6;
    int m0 = blockIdx.x * 128;
    int n0 = blockIdx.y * 128;
    int wm = (wave >> 1) * 64;
    int wn = (wave & 1) * 64;

    floatx4 acc[4][4] = {};

    int lr = lane & 15;
    int kq = (lane >> 4) * 8;

    // staging chunk assignment: 512 16B-chunks per 128x32 bf16 tile, 2 per thread
    int c0 = tid;
    int c1 = tid + 256;
    int r0 = c0 >> 2, o0 = (c0 & 3) * 8;
    int r1 = c1 >> 2, o1 = (c1 & 3) * 8;

    const __hip_bfloat16* gA0 = xb + (size_t)(m0 + r0) * K_DIM + o0;
    const __hip_bfloat16* gA1 = xb + (size_t)(m0 + r1) * K_DIM + o1;
    const __hip_bfloat16* gB0 = qb + (size_t)(n0 + r0) * K_DIM + o0;
    const __hip_bfloat16* gB1 = qb + (size_t)(n0 + r1) * K_DIM + o1;

    for (int k0 = 0; k0 < K_DIM; k0 += 32) {
        load16(gA0 + k0, &lsA[c0 * 8]);
        load16(gA1 + k0, &lsA[c1 * 8]);
        load16(gB0 + k0, &lsB[c0 * 8]);
        load16(gB1 + k0, &lsB[c1 * 8]);
        __syncthreads();

        short8 a[4], b[4];
        #pragma unroll
        for (int i = 0; i < 4; i++) {
            a[i] = *(const short8*)&lsA[(wm + i * 16 + lr) * 32 + kq];
            b[i] = *(const short8*)&lsB[(wn + i * 16 + lr) * 32 + kq];
        }
        #pragma unroll
        for (int mi = 0; mi < 4; mi++)
            #pragma unroll
            for (int ni = 0; ni < 4; ni++)
                acc[mi][ni] = __builtin_amdgcn_mfma_f32_16x16x32_bf16(a[mi], b[ni], acc[mi][ni], 0, 0, 0);
        __syncthreads();
    }

    // epilogue: C/D layout col=lane&15, row=(lane>>4)*4+reg
    int cn = lane & 15;
    int rq = (lane >> 4) * 4;
    #pragma unroll
    for (int ni = 0; ni < 4; ni++) {
        int col = n0 + wn + ni * 16 + cn;
        float s = scales[col];
        #pragma unroll
        for (int mi = 0; mi < 4; mi++) {
            int rowb = m0 + wm + mi * 16 + rq;
            #pragma unroll
            for (int r = 0; r < 4; r++) {
                out[(size_t)(rowb + r) * N_DIM + col] = acc[mi][ni][r] * s;
            }
        }
    }
}

extern "C" void kernel_launch(void* const* d_in, const int* in_sizes, int n_in,
                              void* d_out, int out_size, void* d_ws, size_t ws_size,
                              hipStream_t stream) {
    const float* x = (const float*)d_in[0];
    const float* w = (const float*)d_in[1];
    float* out = (float*)d_out;

    char* ws = (char*)d_ws;
    __hip_bfloat16* xb = (__hip_bfloat16*)ws;                                   // 67,108,864 B
    __hip_bfloat16* qb = (__hip_bfloat16*)(ws + (size_t)M_DIM * K_DIM * 2);     // 33,554,432 B
    float* scales = (float*)(ws + (size_t)M_DIM * K_DIM * 2 + (size_t)N_DIM * K_DIM * 2);  // 16 KiB

    row_scale_kernel<<<N_DIM, 256, 0, stream>>>(w, scales);
    quant_kernel<<<(N_DIM * K_DIM / 4) / 256, 256, 0, stream>>>(w, scales, qb);
    xconv_kernel<<<(M_DIM * K_DIM / 4) / 256, 256, 0, stream>>>(x, xb);
    gemm_kernel<<<dim3(M_DIM / 128, N_DIM / 128), 256, 0, stream>>>(xb, qb, scales, out);
}

// Round 2
// 582.745 us; speedup vs baseline: 1.0494x; 1.0494x over previous
//
#include <hip/hip_runtime.h>
#include <hip/hip_bf16.h>
#include <stdint.h>

#define M_DIM 8192
#define K_DIM 4096
#define N_DIM 4096

typedef __attribute__((ext_vector_type(8))) short short8;
typedef __attribute__((ext_vector_type(4))) float floatx4;

// ---------------- per-row abs-mean scale ----------------
__global__ void row_scale_kernel(const float* __restrict__ w, float* __restrict__ scales) {
    int row = blockIdx.x;
    const float4* wr = (const float4*)(w + (size_t)row * K_DIM);
    double s = 0.0;
    for (int i = threadIdx.x; i < K_DIM / 4; i += 256) {
        float4 v = wr[i];
        s += (double)fabsf(v.x) + (double)fabsf(v.y) + (double)fabsf(v.z) + (double)fabsf(v.w);
    }
    #pragma unroll
    for (int off = 32; off > 0; off >>= 1) s += __shfl_down(s, off);
    __shared__ double partial[4];
    int wave = threadIdx.x >> 6;
    if ((threadIdx.x & 63) == 0) partial[wave] = s;
    __syncthreads();
    if (threadIdx.x == 0) {
        double t = partial[0] + partial[1] + partial[2] + partial[3];
        float m = (float)(t / (double)K_DIM);
        scales[row] = fmaxf(m, 1e-5f);
    }
}

// ---------------- quantize weight to ternary bf16 ----------------
__global__ void quant_kernel(const float* __restrict__ w, const float* __restrict__ scales,
                             __hip_bfloat16* __restrict__ qb) {
    int v = blockIdx.x * blockDim.x + threadIdx.x;  // over K_DIM*N_DIM/4 float4s
    float4 wv = ((const float4*)w)[v];
    float s = scales[v >> 10];  // 1024 float4s per row of 4096
    float q0 = fminf(fmaxf(rintf(wv.x / s), -1.f), 1.f);
    float q1 = fminf(fmaxf(rintf(wv.y / s), -1.f), 1.f);
    float q2 = fminf(fmaxf(rintf(wv.z / s), -1.f), 1.f);
    float q3 = fminf(fmaxf(rintf(wv.w / s), -1.f), 1.f);
    __hip_bfloat16 o[4] = {__float2bfloat16(q0), __float2bfloat16(q1),
                           __float2bfloat16(q2), __float2bfloat16(q3)};
    *(uint2*)(qb + 4 * (size_t)v) = *(uint2*)o;
}

// ---------------- x fp32 -> bf16 ----------------
__global__ void xconv_kernel(const float* __restrict__ x, __hip_bfloat16* __restrict__ xb) {
    int v = blockIdx.x * blockDim.x + threadIdx.x;  // over M_DIM*K_DIM/4 float4s
    float4 xv = ((const float4*)x)[v];
    __hip_bfloat16 o[4] = {__float2bfloat16(xv.x), __float2bfloat16(xv.y),
                           __float2bfloat16(xv.z), __float2bfloat16(xv.w)};
    *(uint2*)(xb + 4 * (size_t)v) = *(uint2*)o;
}

// ---------------- bf16 MFMA GEMM: out = xb @ qb^T * scale[col] ----------------
__device__ __forceinline__ void load16(const void* g, void* l) {
    __builtin_amdgcn_global_load_lds((const __attribute__((address_space(1))) uint32_t*)g,
                                     (__attribute__((address_space(3))) uint32_t*)l, 16, 0, 0);
}

// LDS layout with XOR-swizzle: chunk index c = r*4 + slot (slot = 0..3, 8 bf16 each).
// Slot `s` of row r holds global k-chunk q_g = s ^ ((r>>1)&3).
// Read of row rr, k-chunk q comes from LDS element (rr*4 + (q ^ ((rr>>1)&3))) * 8.
// Bank quad at read = 4*(lr&1) + (q ^ ((lr>>1)&3)) -> covers all 8 quads twice per
// 16-lane group -> conflict-free (2-way floor only).
__global__ __launch_bounds__(256) void gemm_kernel(const __hip_bfloat16* __restrict__ xb,
                                                   const __hip_bfloat16* __restrict__ qb,
                                                   const float* __restrict__ scales,
                                                   float* __restrict__ out) {
    __shared__ __align__(16) __hip_bfloat16 lsA[128 * 32];
    __shared__ __align__(16) __hip_bfloat16 lsB[128 * 32];
    int tid = threadIdx.x;
    int lane = tid & 63;
    int wave = tid >> 6;

    // XCD-aware remap: 2048 blocks, xcd = bid&7 owns an 8(M)x32(N) tile region,
    // traversed n-major in 4-row groups -> ~5MB L2 working set per XCD.
    int bid = blockIdx.x;
    int xcd = bid & 7;
    int loc = bid >> 3;            // 0..255
    int gm = loc >> 7;             // 0..1 (which group of 4 m-rows)
    int rem = loc & 127;
    int n_idx = rem >> 2;          // 0..31
    int m_idx = (rem & 3) + gm * 4;
    int m0 = (xcd * 8 + m_idx) * 128;
    int n0 = n_idx * 128;

    int wm = (wave >> 1) * 64;
    int wn = (wave & 1) * 64;

    floatx4 acc[4][4] = {};

    int lr = lane & 15;
    int q = lane >> 4;             // k-chunk 0..3 wanted by this lane

    // staging chunk assignment: 512 16B-chunks per 128x32 tile, 2 per thread
    int c0 = tid;
    int c1 = tid + 256;
    int r0 = c0 >> 2, o0 = (((c0 & 3) ^ ((r0 >> 1) & 3))) * 8;
    int r1 = c1 >> 2, o1 = (((c1 & 3) ^ ((r1 >> 1) & 3))) * 8;

    const __hip_bfloat16* gA0 = xb + (size_t)(m0 + r0) * K_DIM + o0;
    const __hip_bfloat16* gA1 = xb + (size_t)(m0 + r1) * K_DIM + o1;
    const __hip_bfloat16* gB0 = qb + (size_t)(n0 + r0) * K_DIM + o0;
    const __hip_bfloat16* gB1 = qb + (size_t)(n0 + r1) * K_DIM + o1;

    for (int k0 = 0; k0 < K_DIM; k0 += 32) {
        load16(gA0 + k0, &lsA[c0 * 8]);
        load16(gA1 + k0, &lsA[c1 * 8]);
        load16(gB0 + k0, &lsB[c0 * 8]);
        load16(gB1 + k0, &lsB[c1 * 8]);
        __syncthreads();

        short8 a[4], b[4];
        #pragma unroll
        for (int i = 0; i < 4; i++) {
            int ra = wm + i * 16 + lr;
            int rb = wn + i * 16 + lr;
            a[i] = *(const short8*)&lsA[(ra * 4 + (q ^ ((ra >> 1) & 3))) * 8];
            b[i] = *(const short8*)&lsB[(rb * 4 + (q ^ ((rb >> 1) & 3))) * 8];
        }
        #pragma unroll
        for (int mi = 0; mi < 4; mi++)
            #pragma unroll
            for (int ni = 0; ni < 4; ni++)
                acc[mi][ni] = __builtin_amdgcn_mfma_f32_16x16x32_bf16(a[mi], b[ni], acc[mi][ni], 0, 0, 0);
        __syncthreads();
    }

    // epilogue: C/D layout col=lane&15, row=(lane>>4)*4+reg
    int cn = lane & 15;
    int rq = (lane >> 4) * 4;
    #pragma unroll
    for (int ni = 0; ni < 4; ni++) {
        int col = n0 + wn + ni * 16 + cn;
        float s = scales[col];
        #pragma unroll
        for (int mi = 0; mi < 4; mi++) {
            int rowb = m0 + wm + mi * 16 + rq;
            #pragma unroll
            for (int r = 0; r < 4; r++) {
                out[(size_t)(rowb + r) * N_DIM + col] = acc[mi][ni][r] * s;
            }
        }
    }
}

extern "C" void kernel_launch(void* const* d_in, const int* in_sizes, int n_in,
                              void* d_out, int out_size, void* d_ws, size_t ws_size,
                              hipStream_t stream) {
    const float* x = (const float*)d_in[0];
    const float* w = (const float*)d_in[1];
    float* out = (float*)d_out;

    char* ws = (char*)d_ws;
    __hip_bfloat16* xb = (__hip_bfloat16*)ws;                                   // 67,108,864 B
    __hip_bfloat16* qb = (__hip_bfloat16*)(ws + (size_t)M_DIM * K_DIM * 2);     // 33,554,432 B
    float* scales = (float*)(ws + (size_t)M_DIM * K_DIM * 2 + (size_t)N_DIM * K_DIM * 2);  // 16 KiB

    row_scale_kernel<<<N_DIM, 256, 0, stream>>>(w, scales);
    quant_kernel<<<(N_DIM * K_DIM / 4) / 256, 256, 0, stream>>>(w, scales, qb);
    xconv_kernel<<<(M_DIM * K_DIM / 4) / 256, 256, 0, stream>>>(x, xb);
    gemm_kernel<<<M_DIM / 128 * N_DIM / 128, 256, 0, stream>>>(xb, qb, scales, out);
}

// Round 3
// 545.479 us; speedup vs baseline: 1.1211x; 1.0683x over previous
//
#include <hip/hip_runtime.h>
#include <hip/hip_bf16.h>
#include <stdint.h>

#define M_DIM 8192
#define K_DIM 4096
#define N_DIM 4096

typedef __attribute__((ext_vector_type(8))) short short8;
typedef __attribute__((ext_vector_type(4))) float floatx4;

// ---------------- fused per-row abs-mean scale + ternary quantize ----------------
// One block per weight row: compute scale, broadcast, quantize (w read once).
__global__ void fused_scale_quant(const float* __restrict__ w, float* __restrict__ scales,
                                  __hip_bfloat16* __restrict__ qb) {
    int row = blockIdx.x;
    const float4* wr = (const float4*)(w + (size_t)row * K_DIM);
    float4 v[4];
    double s = 0.0;
    #pragma unroll
    for (int i = 0; i < 4; i++) {
        v[i] = wr[threadIdx.x + 256 * i];
        s += (double)fabsf(v[i].x) + (double)fabsf(v[i].y) +
             (double)fabsf(v[i].z) + (double)fabsf(v[i].w);
    }
    #pragma unroll
    for (int off = 32; off > 0; off >>= 1) s += __shfl_down(s, off);
    __shared__ double partial[4];
    __shared__ float s_scale;
    int wave = threadIdx.x >> 6;
    if ((threadIdx.x & 63) == 0) partial[wave] = s;
    __syncthreads();
    if (threadIdx.x == 0) {
        double t = partial[0] + partial[1] + partial[2] + partial[3];
        float m = (float)(t / (double)K_DIM);
        m = fmaxf(m, 1e-5f);
        scales[row] = m;
        s_scale = m;
    }
    __syncthreads();
    float sc = s_scale;
    __hip_bfloat16* qr = qb + (size_t)row * K_DIM;
    #pragma unroll
    for (int i = 0; i < 4; i++) {
        float q0 = fminf(fmaxf(rintf(v[i].x / sc), -1.f), 1.f);
        float q1 = fminf(fmaxf(rintf(v[i].y / sc), -1.f), 1.f);
        float q2 = fminf(fmaxf(rintf(v[i].z / sc), -1.f), 1.f);
        float q3 = fminf(fmaxf(rintf(v[i].w / sc), -1.f), 1.f);
        __hip_bfloat16 o[4] = {__float2bfloat16(q0), __float2bfloat16(q1),
                               __float2bfloat16(q2), __float2bfloat16(q3)};
        *(uint2*)(qr + 4 * (threadIdx.x + 256 * i)) = *(uint2*)o;
    }
}

// ---------------- x fp32 -> bf16 (8 elements/thread, 16B store) ----------------
__global__ void xconv_kernel(const float* __restrict__ x, __hip_bfloat16* __restrict__ xb) {
    size_t v = (size_t)blockIdx.x * blockDim.x + threadIdx.x;  // over M*K/8 groups
    float4 a = ((const float4*)x)[2 * v];
    float4 b = ((const float4*)x)[2 * v + 1];
    __hip_bfloat16 o[8] = {__float2bfloat16(a.x), __float2bfloat16(a.y),
                           __float2bfloat16(a.z), __float2bfloat16(a.w),
                           __float2bfloat16(b.x), __float2bfloat16(b.y),
                           __float2bfloat16(b.z), __float2bfloat16(b.w)};
    *(uint4*)(xb + 8 * v) = *(uint4*)o;
}

// ---------------- bf16 MFMA GEMM: out = xb @ qb^T * scale[col] ----------------
__device__ __forceinline__ void load16(const void* g, void* l) {
    __builtin_amdgcn_global_load_lds((const __attribute__((address_space(1))) uint32_t*)g,
                                     (__attribute__((address_space(3))) uint32_t*)l, 16, 0, 0);
}

// LDS k-chunk XOR swizzle (round-1) keeps main-loop ds_read conflict-free.
// Epilogue: per-wave LDS transpose (stride 68 -> 2-way free both phases) so
// global stores are 256B-contiguous dwordx4 (no partial-line write-allocate).
__global__ __launch_bounds__(256) void gemm_kernel(const __hip_bfloat16* __restrict__ xb,
                                                   const __hip_bfloat16* __restrict__ qb,
                                                   const float* __restrict__ scales,
                                                   float* __restrict__ out) {
    __shared__ __align__(16) char smem[17408];  // 16KB staging, 17408B epilogue
    __hip_bfloat16* lsA = (__hip_bfloat16*)smem;
    __hip_bfloat16* lsB = (__hip_bfloat16*)(smem + 8192);
    int tid = threadIdx.x;
    int lane = tid & 63;
    int wave = tid >> 6;

    // XCD-aware remap: xcd = bid&7 owns an 8(M)x32(N) tile region.
    int bid = blockIdx.x;
    int xcd = bid & 7;
    int loc = bid >> 3;
    int gm = loc >> 7;
    int rem = loc & 127;
    int n_idx = rem >> 2;
    int m_idx = (rem & 3) + gm * 4;
    int m0 = (xcd * 8 + m_idx) * 128;
    int n0 = n_idx * 128;

    int wm = (wave >> 1) * 64;
    int wn = (wave & 1) * 64;

    floatx4 acc[4][4] = {};

    int lr = lane & 15;
    int q = lane >> 4;

    // staging: 512 16B-chunks per 128x32 tile, 2 per thread, XOR-swizzled slots
    int c0 = tid;
    int c1 = tid + 256;
    int r0 = c0 >> 2, o0 = (((c0 & 3) ^ ((r0 >> 1) & 3))) * 8;
    int r1 = c1 >> 2, o1 = (((c1 & 3) ^ ((r1 >> 1) & 3))) * 8;

    const __hip_bfloat16* gA0 = xb + (size_t)(m0 + r0) * K_DIM + o0;
    const __hip_bfloat16* gA1 = xb + (size_t)(m0 + r1) * K_DIM + o1;
    const __hip_bfloat16* gB0 = qb + (size_t)(n0 + r0) * K_DIM + o0;
    const __hip_bfloat16* gB1 = qb + (size_t)(n0 + r1) * K_DIM + o1;

    for (int k0 = 0; k0 < K_DIM; k0 += 32) {
        load16(gA0 + k0, &lsA[c0 * 8]);
        load16(gA1 + k0, &lsA[c1 * 8]);
        load16(gB0 + k0, &lsB[c0 * 8]);
        load16(gB1 + k0, &lsB[c1 * 8]);
        __syncthreads();

        short8 a[4], b[4];
        #pragma unroll
        for (int i = 0; i < 4; i++) {
            int ra = wm + i * 16 + lr;
            int rb = wn + i * 16 + lr;
            a[i] = *(const short8*)&lsA[(ra * 4 + (q ^ ((ra >> 1) & 3))) * 8];
            b[i] = *(const short8*)&lsB[(rb * 4 + (q ^ ((rb >> 1) & 3))) * 8];
        }
        #pragma unroll
        for (int mi = 0; mi < 4; mi++)
            #pragma unroll
            for (int ni = 0; ni < 4; ni++)
                acc[mi][ni] = __builtin_amdgcn_mfma_f32_16x16x32_bf16(a[mi], b[ni], acc[mi][ni], 0, 0, 0);
        __syncthreads();
    }

    // ---- epilogue: LDS transpose per wave, then coalesced 256B stores ----
    // C/D layout: col=lane&15, row=(lane>>4)*4+reg
    float* epi = (float*)smem + wave * (16 * 68);  // 16 rows x stride 68
    int cn = lane & 15;
    int qd = lane >> 4;
    float sc[4];
    #pragma unroll
    for (int ni = 0; ni < 4; ni++) sc[ni] = scales[n0 + wn + ni * 16 + cn];

    #pragma unroll
    for (int mi = 0; mi < 4; mi++) {
        // stage 16x64 (scaled) into LDS
        #pragma unroll
        for (int ni = 0; ni < 4; ni++)
            #pragma unroll
            for (int r = 0; r < 4; r++)
                epi[(qd * 4 + r) * 68 + ni * 16 + cn] = acc[mi][ni][r] * sc[ni];
        // read back coalesced: 4 passes of 4 rows x 64 cols
        int rowbase = m0 + wm + mi * 16;
        #pragma unroll
        for (int p = 0; p < 4; p++) {
            float4 vv = *(const float4*)&epi[(p * 4 + qd) * 68 + cn * 4];
            *(float4*)&out[(size_t)(rowbase + p * 4 + qd) * N_DIM + n0 + wn + cn * 4] = vv;
        }
    }
}

extern "C" void kernel_launch(void* const* d_in, const int* in_sizes, int n_in,
                              void* d_out, int out_size, void* d_ws, size_t ws_size,
                              hipStream_t stream) {
    const float* x = (const float*)d_in[0];
    const float* w = (const float*)d_in[1];
    float* out = (float*)d_out;

    char* ws = (char*)d_ws;
    __hip_bfloat16* xb = (__hip_bfloat16*)ws;                                   // 67,108,864 B
    __hip_bfloat16* qb = (__hip_bfloat16*)(ws + (size_t)M_DIM * K_DIM * 2);     // 33,554,432 B
    float* scales = (float*)(ws + (size_t)M_DIM * K_DIM * 2 + (size_t)N_DIM * K_DIM * 2);  // 16 KiB

    fused_scale_quant<<<N_DIM, 256, 0, stream>>>(w, scales, qb);
    xconv_kernel<<<(M_DIM * K_DIM / 8) / 256, 256, 0, stream>>>(x, xb);
    gemm_kernel<<<M_DIM / 128 * N_DIM / 128, 256, 0, stream>>>(xb, qb, scales, out);
}